// Round 9
// baseline (165.204 us; speedup 1.0000x reference)
//
#include <hip/hip_runtime.h>
#include <hip/hip_fp8.h>

#define NROWS 8192
#define DDIM  512
#define INV_TAU 14.285714285714286f

typedef float f32x4  __attribute__((ext_vector_type(4)));
typedef float f32x16 __attribute__((ext_vector_type(16)));
typedef long  longx2 __attribute__((ext_vector_type(2)));

__device__ static inline unsigned char f2e4(float f) {
  __hip_fp8_e4m3 h(f); return (unsigned char)h.__x;
}
__device__ static inline float e4f(unsigned char b) {
  __hip_fp8_e4m3 h; h.__x = b; return (float)h;
}

__device__ static inline void load_lds16(const void* g, void* l) {
  __builtin_amdgcn_global_load_lds(
      (const __attribute__((address_space(1))) void*)g,
      (__attribute__((address_space(3))) void*)l, 16, 0, 0);
}

// ---------------- normalize: fp32 rows -> fp8 e4m3, sigma-permuted -----------
// Within each 128B k-segment, chunk c (8B, k=c*8..c*8+7; c = kk*2+h for MFMA
// sub-block kk in 0..7... per segment c=2*kk+h with kk in 0..7? c in 0..15,
// kk = c>>1, h = c&1) is stored at pos8 = T*2+u, T = ((c>>2)<<1)|(c&1),
// u = (c>>1)&1.  So a b128 read at slot16 T returns chunks kk=2q (lo) and
// kk=2q+1 (hi) for half h, where T = 2q+h.  Dot products are invariant since
// both zi and zj use the same permutation.
__global__ __launch_bounds__(256) void norm_kernel(
    const float* __restrict__ zi, const float* __restrict__ zj,
    unsigned char* __restrict__ ziN, unsigned char* __restrict__ zjN) {
  int rid = blockIdx.x * 4 + (threadIdx.x >> 6);   // 0..16383
  int lane = threadIdx.x & 63;
  const float* src;
  unsigned char* dst;
  if (rid < NROWS) { src = zi + (size_t)rid * DDIM; dst = ziN + (size_t)rid * DDIM; }
  else             { src = zj + (size_t)(rid - NROWS) * DDIM; dst = zjN + (size_t)(rid - NROWS) * DDIM; }
  float4 v0 = *(const float4*)(src + lane * 8);
  float4 v1 = *(const float4*)(src + lane * 8 + 4);
  float ss = v0.x*v0.x + v0.y*v0.y + v0.z*v0.z + v0.w*v0.w
           + v1.x*v1.x + v1.y*v1.y + v1.z*v1.z + v1.w*v1.w;
  #pragma unroll
  for (int off = 1; off < 64; off <<= 1) ss += __shfl_xor(ss, off);
  float scale = 1.0f / fmaxf(sqrtf(ss), 1e-8f);
  unsigned long long w = 0;
  w |= (unsigned long long)f2e4(v0.x * scale);
  w |= (unsigned long long)f2e4(v0.y * scale) << 8;
  w |= (unsigned long long)f2e4(v0.z * scale) << 16;
  w |= (unsigned long long)f2e4(v0.w * scale) << 24;
  w |= (unsigned long long)f2e4(v1.x * scale) << 32;
  w |= (unsigned long long)f2e4(v1.y * scale) << 40;
  w |= (unsigned long long)f2e4(v1.z * scale) << 48;
  w |= (unsigned long long)f2e4(v1.w * scale) << 56;
  int seg = lane >> 4;          // 128B segment
  int c   = lane & 15;          // chunk within segment
  int T   = ((c >> 2) << 1) | (c & 1);
  int u   = (c >> 1) & 1;
  *(unsigned long long*)(dst + seg * 128 + (T * 2 + u) * 8) = w;
}

// ---------------- zero row/col accumulators (contiguous 16384 floats) --------
__global__ __launch_bounds__(256) void zero_kernel(float* __restrict__ p) {
  p[blockIdx.x * 256 + threadIdx.x] = 0.0f;
}

// ---------------- pos[i] = dot(ziN[i], zjN[i]) / tau (fp8, perm-invariant) ---
__global__ __launch_bounds__(256) void pos_kernel(
    const unsigned char* __restrict__ ziN, const unsigned char* __restrict__ zjN,
    float* __restrict__ pos) {
  int row = blockIdx.x * 4 + (threadIdx.x >> 6);
  int lane = threadIdx.x & 63;
  unsigned long long a8 = *(const unsigned long long*)(ziN + (size_t)row * DDIM + lane * 8);
  unsigned long long b8 = *(const unsigned long long*)(zjN + (size_t)row * DDIM + lane * 8);
  float s = 0.0f;
  #pragma unroll
  for (int j = 0; j < 8; ++j)
    s += e4f((unsigned char)(a8 >> (8 * j))) * e4f((unsigned char)(b8 >> (8 * j)));
  #pragma unroll
  for (int off = 1; off < 64; off <<= 1) s += __shfl_xor(s, off);
  if (lane == 0) pos[row] = s * INV_TAU;
}

// ---------------- fused sim GEMM + exp + row/col sum (fp8 32x32, BK=128) -----
// 128x128 tile, BK=128 (4 K-tiles), 4 waves 2x2 (64x64 each, 2x2 frags of
// 32x32), single-buffer LDS 32KB, plain __syncthreads loop, 4 blocks/CU.
// LDS rows 128B (all 32 banks); slot16 XOR t^(row&7) on staging SOURCE and
// on frag ds_read_b128 -> uniform bank sweep (R7-verified pattern).
__global__ __launch_bounds__(256, 4) void sim_fp8(
    const unsigned char* __restrict__ ziN, const unsigned char* __restrict__ zjN,
    float* __restrict__ row_sum, float* __restrict__ col_sum) {
  __shared__ __align__(16) unsigned char As[16384];   // 128 rows x 128 B
  __shared__ __align__(16) unsigned char Bs[16384];

  const int tid  = threadIdx.x;
  const int lane = tid & 63;
  const int wid  = tid >> 6;
  const int wr   = wid >> 1, wc = wid & 1;   // 2x2 waves, 64x64 each
  const int cl   = lane & 31;                // operand row / C col
  const int h    = lane >> 5;
  const int brow = blockIdx.y * 128;
  const int bcol = blockIdx.x * 128;

  f32x16 acc[2][2] = {};

  #pragma unroll 1
  for (int kt = 0; kt < 4; ++kt) {
    if (kt) __syncthreads();     // WAR: prior reads done before overwrite
    #pragma unroll
    for (int q = 0; q < 4; ++q) {
      int idx = q * 256 + tid;             // 0..1023
      int row = idx >> 3;                  // 0..127
      int t   = idx & 7;                   // slot16
      load_lds16(ziN + (size_t)(brow + row) * DDIM + kt * 128 + ((t ^ (row & 7)) << 4),
                 (char*)As + idx * 16);
    }
    #pragma unroll
    for (int q = 0; q < 4; ++q) {
      int idx = q * 256 + tid;
      int row = idx >> 3;
      int t   = idx & 7;
      load_lds16(zjN + (size_t)(bcol + row) * DDIM + kt * 128 + ((t ^ (row & 7)) << 4),
                 (char*)Bs + idx * 16);
    }
    __syncthreads();             // RAW: staged data visible (vmcnt drain)
    #pragma unroll
    for (int q = 0; q < 4; ++q) {          // slot16 pair: kk = 2q, 2q+1
      longx2 a[2], b[2];
      #pragma unroll
      for (int mf = 0; mf < 2; ++mf) {
        int r = wr * 64 + mf * 32 + cl;
        a[mf] = *(const longx2*)((const char*)As + r * 128 + (((q * 2 + h) ^ (r & 7)) << 4));
      }
      #pragma unroll
      for (int nf = 0; nf < 2; ++nf) {
        int r = wc * 64 + nf * 32 + cl;
        b[nf] = *(const longx2*)((const char*)Bs + r * 128 + (((q * 2 + h) ^ (r & 7)) << 4));
      }
      #pragma unroll
      for (int mf = 0; mf < 2; ++mf)
        #pragma unroll
        for (int nf = 0; nf < 2; ++nf) {
          acc[mf][nf] = __builtin_amdgcn_mfma_f32_32x32x16_fp8_fp8(
              a[mf][0], b[nf][0], acc[mf][nf], 0, 0, 0);
          acc[mf][nf] = __builtin_amdgcn_mfma_f32_32x32x16_fp8_fp8(
              a[mf][1], b[nf][1], acc[mf][nf], 0, 0, 0);
        }
    }
  }

  // epilogue (m74 32x32 C layout: col=lane&31, row=(reg&3)+8*(reg>>2)+4*h)
  const float Cc = INV_TAU * 1.4426950408889634f;
  #pragma unroll
  for (int mf = 0; mf < 2; ++mf)
    #pragma unroll
    for (int nf = 0; nf < 2; ++nf) {
      int gj = bcol + wc * 64 + nf * 32 + cl;
      #pragma unroll
      for (int reg = 0; reg < 16; ++reg) {
        int gi = brow + wr * 64 + mf * 32 + (reg & 3) + 8 * (reg >> 2) + 4 * h;
        float e = exp2f((acc[mf][nf][reg] - 1.0f) * Cc);
        acc[mf][nf][reg] = (gi == gj) ? 0.0f : e;
      }
    }
  // column sums: lane holds one col per nf; sum 32 rows (regs+mf), fold halves
  #pragma unroll
  for (int nf = 0; nf < 2; ++nf) {
    float cs = 0.0f;
    #pragma unroll
    for (int mf = 0; mf < 2; ++mf)
      #pragma unroll
      for (int reg = 0; reg < 16; ++reg) cs += acc[mf][nf][reg];
    cs += __shfl_xor(cs, 32);
    if (lane < 32) atomicAdd(&col_sum[bcol + wc * 64 + nf * 32 + lane], cs);
  }
  // row sums: per (mf, reg): sum nf, reduce across the 32-lane group
  #pragma unroll
  for (int mf = 0; mf < 2; ++mf)
    #pragma unroll
    for (int reg = 0; reg < 16; ++reg) {
      float rs = acc[mf][0][reg] + acc[mf][1][reg];
      rs += __shfl_xor(rs, 1);
      rs += __shfl_xor(rs, 2);
      rs += __shfl_xor(rs, 4);
      rs += __shfl_xor(rs, 8);
      rs += __shfl_xor(rs, 16);
      if (cl == 0)
        atomicAdd(&row_sum[brow + wr * 64 + mf * 32 + (reg & 3) + 8 * (reg >> 2) + 4 * h], rs);
    }
}

// ---------------- finalize: 3 scalars ----------------------------------------
__global__ __launch_bounds__(256) void finalize_kernel(
    const float* __restrict__ row_sum, const float* __restrict__ col_sum,
    const float* __restrict__ pos, float* __restrict__ out) {
  __shared__ float sA[4], sB[4];
  float sa = 0.0f, sb = 0.0f;
  for (int i = threadIdx.x; i < NROWS; i += 256) {
    float p = pos[i];
    sa += (INV_TAU + __logf(row_sum[i])) - p;
    sb += (INV_TAU + __logf(col_sum[i])) - p;
  }
  #pragma unroll
  for (int off = 1; off < 64; off <<= 1) {
    sa += __shfl_xor(sa, off);
    sb += __shfl_xor(sb, off);
  }
  if ((threadIdx.x & 63) == 0) { sA[threadIdx.x >> 6] = sa; sB[threadIdx.x >> 6] = sb; }
  __syncthreads();
  if (threadIdx.x == 0) {
    float ta = sA[0] + sA[1] + sA[2] + sA[3];
    float tb = sB[0] + sB[1] + sB[2] + sB[3];
    float e2t = ta / (float)NROWS;
    float t2e = tb / (float)NROWS;
    out[0] = 0.5f * (e2t + t2e);
    out[1] = e2t;
    out[2] = t2e;
  }
}

extern "C" void kernel_launch(void* const* d_in, const int* in_sizes, int n_in,
                              void* d_out, int out_size, void* d_ws, size_t ws_size,
                              hipStream_t stream) {
  const float* z_i = (const float*)d_in[0];
  const float* z_j = (const float*)d_in[1];
  float* out = (float*)d_out;
  char* ws = (char*)d_ws;
  unsigned char* ziN = (unsigned char*)ws;                         // 4 MB
  unsigned char* zjN = (unsigned char*)(ws + 4194304);             // 4 MB
  float* row_sum = (float*)(ws + 8388608);                         // 32 KB
  float* col_sum = row_sum + NROWS;                                // 32 KB (contiguous)
  float* pos     = col_sum + NROWS;                                // 32 KB

  norm_kernel<<<4096, 256, 0, stream>>>(z_i, z_j, ziN, zjN);
  zero_kernel<<<64, 256, 0, stream>>>(row_sum);                    // zeros row+col (contiguous)
  pos_kernel<<<2048, 256, 0, stream>>>(ziN, zjN, pos);
  dim3 grid(64, 64);
  sim_fp8<<<grid, 256, 0, stream>>>(ziN, zjN, row_sum, col_sum);
  finalize_kernel<<<1, 256, 0, stream>>>(row_sum, col_sum, pos, out);
}

// Round 10
// 113.750 us; speedup vs baseline: 1.4523x; 1.4523x over previous
//
#include <hip/hip_runtime.h>
#include <hip/hip_fp8.h>

#define NROWS 8192
#define DDIM  512
#define INV_TAU 14.285714285714286f

typedef float f32x16 __attribute__((ext_vector_type(16)));
typedef long  longx2 __attribute__((ext_vector_type(2)));

__device__ static inline unsigned char f2e4(float f) {
  __hip_fp8_e4m3 h(f); return (unsigned char)h.__x;
}
__device__ static inline float e4f(unsigned char b) {
  __hip_fp8_e4m3 h; h.__x = b; return (float)h;
}

// ---------------- layout ------------------------------------------------------
// Fragment-major panels: panel p = rows [32p, 32p+32), 16 KB each.
// Unit u (1 KB) holds k-blocks kb=2u,2u+1: byte addr within panel =
//   u*1024 + lane*16, where lane = h*32 + r gives (row r, k-half h) the
//   longx2 {kb=2u, kb=2u+1}.  Chunk c (8 fp8, k=[8c,8c+8)) of row r lives at
//   p*16384 + (c>>2)*1024 + ((c&1)*32 + r)*16 + ((c>>1)&1)*8.
// This makes sim's operand loads single coalesced global_load_dwordx4
// matching the R9-verified mfma_f32_32x32x16_fp8_fp8 fragment mapping.

// ---------------- normalize: fp32 rows -> fp8 e4m3 panels ---------------------
__global__ __launch_bounds__(256) void norm_kernel(
    const float* __restrict__ zi, const float* __restrict__ zj,
    unsigned char* __restrict__ ziN, unsigned char* __restrict__ zjN) {
  int rid = blockIdx.x * 4 + (threadIdx.x >> 6);   // 0..16383
  int lane = threadIdx.x & 63;
  const float* src;
  unsigned char* dstbase;
  int row;
  if (rid < NROWS) { src = zi + (size_t)rid * DDIM; dstbase = ziN; row = rid; }
  else             { src = zj + (size_t)(rid - NROWS) * DDIM; dstbase = zjN; row = rid - NROWS; }
  float4 v0 = *(const float4*)(src + lane * 8);
  float4 v1 = *(const float4*)(src + lane * 8 + 4);
  float ss = v0.x*v0.x + v0.y*v0.y + v0.z*v0.z + v0.w*v0.w
           + v1.x*v1.x + v1.y*v1.y + v1.z*v1.z + v1.w*v1.w;
  #pragma unroll
  for (int off = 1; off < 64; off <<= 1) ss += __shfl_xor(ss, off);
  float scale = 1.0f / fmaxf(sqrtf(ss), 1e-8f);
  unsigned long long w = 0;
  w |= (unsigned long long)f2e4(v0.x * scale);
  w |= (unsigned long long)f2e4(v0.y * scale) << 8;
  w |= (unsigned long long)f2e4(v0.z * scale) << 16;
  w |= (unsigned long long)f2e4(v0.w * scale) << 24;
  w |= (unsigned long long)f2e4(v1.x * scale) << 32;
  w |= (unsigned long long)f2e4(v1.y * scale) << 40;
  w |= (unsigned long long)f2e4(v1.z * scale) << 48;
  w |= (unsigned long long)f2e4(v1.w * scale) << 56;
  int p = row >> 5, r = row & 31, c = lane;     // chunk index = lane
  *(unsigned long long*)(dstbase + (size_t)p * 16384 + (c >> 2) * 1024 +
                         ((c & 1) * 32 + r) * 16 + ((c >> 1) & 1) * 8) = w;
}

// ---------------- zero row/col accumulators (contiguous 16384 floats) --------
__global__ __launch_bounds__(256) void zero_kernel(float* __restrict__ p) {
  p[blockIdx.x * 256 + threadIdx.x] = 0.0f;
}

// ---------------- pos[i] = dot(ziN[i], zjN[i]) / tau (panel layout) ----------
__global__ __launch_bounds__(256) void pos_kernel(
    const unsigned char* __restrict__ ziN, const unsigned char* __restrict__ zjN,
    float* __restrict__ pos) {
  int row = blockIdx.x * 4 + (threadIdx.x >> 6);
  int lane = threadIdx.x & 63;
  int p = row >> 5, r = row & 31, c = lane;
  size_t off = (size_t)p * 16384 + (c >> 2) * 1024 + ((c & 1) * 32 + r) * 16 + ((c >> 1) & 1) * 8;
  unsigned long long a8 = *(const unsigned long long*)(ziN + off);
  unsigned long long b8 = *(const unsigned long long*)(zjN + off);
  float s = 0.0f;
  #pragma unroll
  for (int j = 0; j < 8; ++j)
    s += e4f((unsigned char)(a8 >> (8 * j))) * e4f((unsigned char)(b8 >> (8 * j)));
  #pragma unroll
  for (int off2 = 1; off2 < 64; off2 <<= 1) s += __shfl_xor(s, off2);
  if (lane == 0) pos[row] = s * INV_TAU;
}

// ---------------- fused sim GEMM + exp + row/col sum (reg-direct, no LDS) ----
// 128x128 tile, 4 waves 2x2 (64x64 each = 2x2 32x32 frags).  Operands loaded
// straight to VGPRs via coalesced dwordx4 from fragment-major panels.
// No LDS, no barriers.  Prefetch depth 1.  XCD-chunked block swizzle.
__global__ __launch_bounds__(256, 4) void sim_reg(
    const unsigned char* __restrict__ Ap, const unsigned char* __restrict__ Bp,
    float* __restrict__ row_sum, float* __restrict__ col_sum) {
  const int tid  = threadIdx.x;
  const int lane = tid & 63;
  const int wid  = tid >> 6;
  const int wr   = wid >> 1, wc = wid & 1;   // 2x2 waves, 64x64 each
  const int cl   = lane & 31;                // operand row / C col
  const int h    = lane >> 5;
  // XCD-chunked swizzle: xcd owns by in [8*xcd, 8*xcd+8), bx-major inner order
  const int orig = blockIdx.x;               // 0..4095
  const int xcd  = orig & 7;
  const int seq  = orig >> 3;                // 0..511
  const int by   = xcd * 8 + (seq & 7);
  const int bx   = seq >> 3;                 // 0..63
  const int brow = by * 128, bcol = bx * 128;

  f32x16 acc[2][2] = {};

  const unsigned char* pa0 = Ap + (size_t)(by * 4 + wr * 2) * 16384 + lane * 16;
  const unsigned char* pa1 = pa0 + 16384;
  const unsigned char* pb0 = Bp + (size_t)(bx * 4 + wc * 2) * 16384 + lane * 16;
  const unsigned char* pb1 = pb0 + 16384;

  longx2 a0 = *(const longx2*)pa0;
  longx2 a1 = *(const longx2*)pa1;
  longx2 b0 = *(const longx2*)pb0;
  longx2 b1 = *(const longx2*)pb1;

  #pragma unroll 4
  for (int u = 0; u < 16; ++u) {
    const int un = ((u + 1) & 15) * 1024;
    longx2 na0 = *(const longx2*)(pa0 + un);
    longx2 na1 = *(const longx2*)(pa1 + un);
    longx2 nb0 = *(const longx2*)(pb0 + un);
    longx2 nb1 = *(const longx2*)(pb1 + un);
    acc[0][0] = __builtin_amdgcn_mfma_f32_32x32x16_fp8_fp8(a0[0], b0[0], acc[0][0], 0, 0, 0);
    acc[0][1] = __builtin_amdgcn_mfma_f32_32x32x16_fp8_fp8(a0[0], b1[0], acc[0][1], 0, 0, 0);
    acc[1][0] = __builtin_amdgcn_mfma_f32_32x32x16_fp8_fp8(a1[0], b0[0], acc[1][0], 0, 0, 0);
    acc[1][1] = __builtin_amdgcn_mfma_f32_32x32x16_fp8_fp8(a1[0], b1[0], acc[1][1], 0, 0, 0);
    acc[0][0] = __builtin_amdgcn_mfma_f32_32x32x16_fp8_fp8(a0[1], b0[1], acc[0][0], 0, 0, 0);
    acc[0][1] = __builtin_amdgcn_mfma_f32_32x32x16_fp8_fp8(a0[1], b1[1], acc[0][1], 0, 0, 0);
    acc[1][0] = __builtin_amdgcn_mfma_f32_32x32x16_fp8_fp8(a1[1], b0[1], acc[1][0], 0, 0, 0);
    acc[1][1] = __builtin_amdgcn_mfma_f32_32x32x16_fp8_fp8(a1[1], b1[1], acc[1][1], 0, 0, 0);
    a0 = na0; a1 = na1; b0 = nb0; b1 = nb1;
  }

  // epilogue (R9-verified 32x32 C layout: col=lane&31, row=(reg&3)+8*(reg>>2)+4*h)
  const float Cc = INV_TAU * 1.4426950408889634f;
  #pragma unroll
  for (int mf = 0; mf < 2; ++mf)
    #pragma unroll
    for (int nf = 0; nf < 2; ++nf) {
      int gj = bcol + wc * 64 + nf * 32 + cl;
      #pragma unroll
      for (int reg = 0; reg < 16; ++reg) {
        int gi = brow + wr * 64 + mf * 32 + (reg & 3) + 8 * (reg >> 2) + 4 * h;
        float e = exp2f((acc[mf][nf][reg] - 1.0f) * Cc);
        acc[mf][nf][reg] = (gi == gj) ? 0.0f : e;
      }
    }
  #pragma unroll
  for (int nf = 0; nf < 2; ++nf) {
    float cs = 0.0f;
    #pragma unroll
    for (int mf = 0; mf < 2; ++mf)
      #pragma unroll
      for (int reg = 0; reg < 16; ++reg) cs += acc[mf][nf][reg];
    cs += __shfl_xor(cs, 32);
    if (lane < 32) atomicAdd(&col_sum[bcol + wc * 64 + nf * 32 + lane], cs);
  }
  #pragma unroll
  for (int mf = 0; mf < 2; ++mf)
    #pragma unroll
    for (int reg = 0; reg < 16; ++reg) {
      float rs = acc[mf][0][reg] + acc[mf][1][reg];
      rs += __shfl_xor(rs, 1);
      rs += __shfl_xor(rs, 2);
      rs += __shfl_xor(rs, 4);
      rs += __shfl_xor(rs, 8);
      rs += __shfl_xor(rs, 16);
      if (cl == 0)
        atomicAdd(&row_sum[brow + wr * 64 + mf * 32 + (reg & 3) + 8 * (reg >> 2) + 4 * h], rs);
    }
}

// ---------------- finalize: 3 scalars ----------------------------------------
__global__ __launch_bounds__(256) void finalize_kernel(
    const float* __restrict__ row_sum, const float* __restrict__ col_sum,
    const float* __restrict__ pos, float* __restrict__ out) {
  __shared__ float sA[4], sB[4];
  float sa = 0.0f, sb = 0.0f;
  for (int i = threadIdx.x; i < NROWS; i += 256) {
    float p = pos[i];
    sa += (INV_TAU + __logf(row_sum[i])) - p;
    sb += (INV_TAU + __logf(col_sum[i])) - p;
  }
  #pragma unroll
  for (int off = 1; off < 64; off <<= 1) {
    sa += __shfl_xor(sa, off);
    sb += __shfl_xor(sb, off);
  }
  if ((threadIdx.x & 63) == 0) { sA[threadIdx.x >> 6] = sa; sB[threadIdx.x >> 6] = sb; }
  __syncthreads();
  if (threadIdx.x == 0) {
    float ta = sA[0] + sA[1] + sA[2] + sA[3];
    float tb = sB[0] + sB[1] + sB[2] + sB[3];
    float e2t = ta / (float)NROWS;
    float t2e = tb / (float)NROWS;
    out[0] = 0.5f * (e2t + t2e);
    out[1] = e2t;
    out[2] = t2e;
  }
}

extern "C" void kernel_launch(void* const* d_in, const int* in_sizes, int n_in,
                              void* d_out, int out_size, void* d_ws, size_t ws_size,
                              hipStream_t stream) {
  const float* z_i = (const float*)d_in[0];
  const float* z_j = (const float*)d_in[1];
  float* out = (float*)d_out;
  char* ws = (char*)d_ws;
  unsigned char* ziN = (unsigned char*)ws;                         // 4 MB (panels)
  unsigned char* zjN = (unsigned char*)(ws + 4194304);             // 4 MB (panels)
  float* row_sum = (float*)(ws + 8388608);                         // 32 KB
  float* col_sum = row_sum + NROWS;                                // 32 KB (contiguous)
  float* pos     = col_sum + NROWS;                                // 32 KB

  norm_kernel<<<4096, 256, 0, stream>>>(z_i, z_j, ziN, zjN);
  zero_kernel<<<64, 256, 0, stream>>>(row_sum);                    // zeros row+col (contiguous)
  pos_kernel<<<2048, 256, 0, stream>>>(ziN, zjN, pos);
  sim_reg<<<4096, 256, 0, stream>>>(ziN, zjN, row_sum, col_sum);
  finalize_kernel<<<1, 256, 0, stream>>>(row_sum, col_sum, pos, out);
}